// Round 19
// baseline (3903.467 us; speedup 1.0000x reference)
//
#include <hip/hip_runtime.h>

typedef _Float16 f16;
typedef __attribute__((ext_vector_type(4))) _Float16 f16x4;
typedef __attribute__((ext_vector_type(8))) _Float16 f16x8;
typedef __attribute__((ext_vector_type(4))) float f32x4;

#define MFMA16(a, b, c) __builtin_amdgcn_mfma_f32_16x16x32_f16(a, b, c, 0, 0, 0)

__device__ __forceinline__ void gll16(const void* g, void* l) {
    __builtin_amdgcn_global_load_lds(
        (const __attribute__((address_space(1))) unsigned int*)g,
        (__attribute__((address_space(3))) unsigned int*)l, 16, 0, 0);
}

#define BAR() __builtin_amdgcn_s_barrier()
// RAW gate for global_load_lds -> ds_read; "memory" clobber only.
#define VMC(n)  asm volatile("s_waitcnt vmcnt(" #n ")" ::: "memory")

// ---------------------------------------------------------------------------
// prep_all: fused {x->f16, enc->f16, W->Wt f16 transposed} in one dispatch.
// ---------------------------------------------------------------------------
__global__ __launch_bounds__(256) void prep_all(
    const float* __restrict__ x, const float* __restrict__ enc,
    const float* __restrict__ Wq, const float* __restrict__ Wk,
    const float* __restrict__ Wv,
    f16* __restrict__ Xh, f16* __restrict__ Eh, f16* __restrict__ Wt)
{
    const int bid = blockIdx.x;
    if (bid < 32768) {
        const float* in = (bid < 16384) ? x : enc;
        f16* out = (bid < 16384) ? Xh : Eh;
        const int b = bid & 16383;
        const size_t i = ((size_t)b * 256 + threadIdx.x) * 8;
        float4 a = *(const float4*)(in + i);
        float4 c = *(const float4*)(in + i + 4);
        f16x8 o;
        o[0] = (f16)a.x; o[1] = (f16)a.y; o[2] = (f16)a.z; o[3] = (f16)a.w;
        o[4] = (f16)c.x; o[5] = (f16)c.y; o[6] = (f16)c.z; o[7] = (f16)c.w;
        *(f16x8*)(out + i) = o;
        return;
    }
    __shared__ float tile[32][33];
    const int id2 = bid - 32768;
    const int w = id2 >> 10;
    const int r = id2 & 1023;
    const int n0 = (r & 31) * 32, k0 = (r >> 5) * 32;
    const float* W = w == 0 ? Wq : (w == 1 ? Wk : Wv);
    f16* dst = Wt + (size_t)w * 1024 * 1024;
    const int tx = threadIdx.x & 31, ty = threadIdx.x >> 5;
#pragma unroll
    for (int i = 0; i < 4; i++)
        tile[ty + i * 8][tx] = W[(size_t)(k0 + ty + i * 8) * 1024 + n0 + tx];
    __syncthreads();
#pragma unroll
    for (int i = 0; i < 4; i++)
        dst[(size_t)(n0 + ty + i * 8) * 1024 + k0 + tx] = (f16)tile[tx][ty + i * 8];
}

// ---------------------------------------------------------------------------
// 256x256 GEMM, BK=32, 64 KiB LDS -> 2 blocks/CU (16 waves: inter-block
// overlap hides barrier/gate stalls, m114). 512 thr = 8 waves (2M x 4N),
// per-wave C 128x64. Rows are 64B; swizzle cb ^= ((row&3)<<4) (4 slots) —
// fragment ds_read_b128 verified conflict-free (8 accesses/bank-group).
// Stage = 4 glls/tile (A:2, B:2), VMC(4) gate lag = 1 full tile.
// EPI: 2 = exp -> f16 S + per-row partial sums -> aux (QK^T)
//      4 = fused Q|K|V projections (blocks [0,512): Q; [512,1536): K|V)
//      5 = PV with inline row-sum inverse from aux
// ---------------------------------------------------------------------------
template <int KD, int EPI>
__global__ __launch_bounds__(512, 4) void gemm8(
    const f16* __restrict__ Ab, const f16* __restrict__ Ab2,
    const f16* __restrict__ Bb,
    const float* __restrict__ b0, const float* __restrict__ b1,
    const float* __restrict__ b2, float scale,
    void* __restrict__ C0, void* __restrict__ C1, void* __restrict__ C2,
    float* __restrict__ aux,
    size_t strA, size_t strB, size_t strC, int ldc, int nbx, int nby)
{
    __shared__ f16 shA[2 * 256 * 32];   // buffer d at d*8192 elems (d*16384 B)
    __shared__ f16 shB[2 * 256 * 32];

    int id = blockIdx.x;
    {
        const int chunk = (int)gridDim.x >> 3;
        id = (id & 7) * chunk + (id >> 3);
    }
    int bx, by, z;
    bool isQ = false;
    if constexpr (EPI == 4) {
        z = 0;
        isQ = (id < 512);
        if (isQ) { by = id & 3; bx = id >> 2; }
        else     { const int id2 = id - 512; by = id2 & 7; bx = id2 >> 3; }
    } else {
        by = id % nby;
        const int r2 = id / nby;
        bx = r2 % nbx;
        z  = r2 / nbx;
    }
    const int bm = bx * 256, bn = by * 256;

    const f16* A;
    const f16* B;
    if constexpr (EPI == 4) {
        A = isQ ? Ab : Ab2;
        B = Bb + (isQ ? (size_t)0 : (size_t)1024 * 1024);
    } else {
        A = Ab + (size_t)z * strA;
        B = Bb + (size_t)z * strB;
    }

    const int t = threadIdx.x, lane = t & 63, wid = t >> 6;
    const int wr = wid >> 2, wc = wid & 3;
    const int fr = lane & 15, kb = (lane >> 4) * 16;   // kb: 0,16,32,48 (full K=32)
    const int sw = (fr & 3) << 4;                      // 4-slot swizzle (64B rows)

    // staging: wave wid covers rows wid*16+(lane>>2) (and +128); lane&3 = col chunk.
    const int srow = wid * 16 + (lane >> 2);
    const int scol = (((lane & 3) * 16) ^ (((lane >> 2) & 3) << 4)) >> 1;  // f16 idx
    const f16* aT0 = A + (size_t)(bm + srow) * KD + scol;
    const f16* bT0 = B + (size_t)(bn + srow) * KD + scol;

    const char* Ab_ = (const char*)shA;
    const char* Bb_ = (const char*)shB;
    const int aoff = (wr * 128 + fr) * 64 + (kb ^ sw);
    const int boff = (wc * 64 + fr) * 64 + (kb ^ sw);

// stage: 2 glls each for A (rows 0-127, 128-255) and B; dest wave-uniform.
#define STG_A(d, kt) do {                                                     \
        const f16* As_ = aT0 + (size_t)(kt) * 32;                             \
        gll16(As_,                     shA + (d) * 8192 + wid * 512);         \
        gll16(As_ + (size_t)128 * KD,  shA + (d) * 8192 + 4096 + wid * 512); } while (0)
#define STG_B(d, kt) do {                                                     \
        const f16* Bs_ = bT0 + (size_t)(kt) * 32;                             \
        gll16(Bs_,                     shB + (d) * 8192 + wid * 512);         \
        gll16(Bs_ + (size_t)128 * KD,  shB + (d) * 8192 + 4096 + wid * 512); } while (0)

    f16x8 af[2][4];     // [mh][i]
    f16x8 bf[2][2];     // [nh][j]
    f32x4 acc[8][4] = {};

#define LDA_(d, mh)                                                           \
    _Pragma("unroll") for (int i_ = 0; i_ < 4; ++i_)                          \
        af[mh][i_] = *(const f16x8*)(Ab_ + (d) * 16384 + aoff +               \
                                     ((mh) * 64 + i_ * 16) * 64);
#define LDB_(d, nh)                                                           \
    _Pragma("unroll") for (int j_ = 0; j_ < 2; ++j_)                          \
        bf[nh][j_] = *(const f16x8*)(Bb_ + (d) * 16384 + boff +               \
                                     ((nh) * 32 + j_ * 16) * 64);

#define MM(mh, nh)                                                            \
    _Pragma("unroll") for (int i_ = 0; i_ < 4; ++i_)                          \
    _Pragma("unroll") for (int j_ = 0; j_ < 2; ++j_)                          \
        acc[(mh) * 4 + i_][(nh) * 2 + j_] =                                   \
            MFMA16(af[mh][i_], bf[nh][j_],                                    \
                   acc[(mh) * 4 + i_][(nh) * 2 + j_]);

// per tile: stage t+1 (4 glls) -> VMC(4) retires stage(t) (issued 1 tile ago)
// -> BAR publishes buf d -> 12 reads + 32 MFMA -> BAR protects d^1 for restage.
#define PTILE(d, kt)                                                          \
    do {                                                                      \
        STG_A((d) ^ 1, (kt) + 1); STG_B((d) ^ 1, (kt) + 1);                   \
        VMC(4);                                                               \
        BAR();                                                                \
        LDA_(d, 0); LDB_(d, 0); LDB_(d, 1); LDA_(d, 1);                       \
        MM(0, 0); MM(0, 1); MM(1, 1); MM(1, 0);                               \
        BAR();                                                                \
    } while (0)

#define PTAIL(d)                                                              \
    do {                                                                      \
        VMC(0);                                                               \
        BAR();                                                                \
        LDA_(d, 0); LDB_(d, 0); LDB_(d, 1); LDA_(d, 1);                       \
        MM(0, 0); MM(0, 1); MM(1, 1); MM(1, 0);                               \
        BAR();                                                                \
    } while (0)

    constexpr int NT = KD / 32;   // 32 or 64, always even

    // prologue: stage tile 0 (4 glls outstanding).
    STG_A(0, 0); STG_B(0, 0);

    for (int ti = 0; ti < NT - 2; ti += 2) {
        PTILE(0, ti);
        PTILE(1, ti + 1);
    }
    PTILE(0, NT - 2);
    PTAIL(1);

    const int fc = lane & 15, rq = (lane >> 4) * 4;

    if constexpr (EPI == 2) {
        float* part = (float*)shA;   // part[256][4] = 4 KB (shA is 32 KB)
        f16* Sp = (f16*)C0 + (size_t)z * strC;
#pragma unroll
        for (int mi = 0; mi < 8; ++mi)
#pragma unroll
            for (int r = 0; r < 4; ++r) {
                const int rl = wr * 128 + mi * 16 + rq + r;
                float ps = 0.f;
#pragma unroll
                for (int nj = 0; nj < 4; ++nj) {
                    const int col = bn + wc * 64 + nj * 16 + fc;
                    f16 eh = (f16)__expf(acc[mi][nj][r]);
                    ps += (float)eh;
                    Sp[(size_t)(bm + rl) * ldc + col] = eh;
                }
#pragma unroll
                for (int o = 1; o < 16; o <<= 1) ps += __shfl_xor(ps, o);
                if (fc == 0) part[rl * 4 + wc] = ps;
            }
        BAR();
        if (t < 256) {
            const float4 p4 = *(const float4*)(part + t * 4);
            aux[((size_t)z * 2048 + bm + t) * 8 + by] = p4.x + p4.y + p4.z + p4.w;
        }
        return;
    }

    if constexpr (EPI == 5) {
        float invr[8][4];
#pragma unroll
        for (int mi = 0; mi < 8; ++mi)
#pragma unroll
            for (int r = 0; r < 4; ++r) {
                const int row = bm + wr * 128 + mi * 16 + rq + r;
                const float4* p = (const float4*)(aux + ((size_t)z * 2048 + row) * 8);
                const float4 a = p[0], b = p[1];
                invr[mi][r] = 1.0f / (a.x + a.y + a.z + a.w + b.x + b.y + b.z + b.w);
            }
#pragma unroll
        for (int nj = 0; nj < 4; ++nj) {
            const int col = bn + wc * 64 + nj * 16 + fc;
#pragma unroll
            for (int mi = 0; mi < 8; ++mi)
#pragma unroll
                for (int r = 0; r < 4; ++r) {
                    const int row = bm + wr * 128 + mi * 16 + rq + r;
                    ((float*)C0 + (size_t)z * strC)[(size_t)row * ldc + col] =
                        acc[mi][nj][r] * invr[mi][r];
                }
        }
        return;
    }

    if constexpr (EPI == 4) {
#pragma unroll
        for (int nj = 0; nj < 4; ++nj) {
            const int col = bn + wc * 64 + nj * 16 + fc;
            if (isQ) {
                const float bv_ = b0[col];
#pragma unroll
                for (int mi = 0; mi < 8; ++mi)
#pragma unroll
                    for (int r = 0; r < 4; ++r) {
                        const int row = bm + wr * 128 + mi * 16 + rq + r;
                        ((f16*)C0)[(size_t)row * 1024 + col] =
                            (f16)((acc[mi][nj][r] + bv_) * scale);
                    }
            } else {
                const float bv_ = (col < 1024) ? b1[col] : b2[col - 1024];
#pragma unroll
                for (int mi = 0; mi < 8; ++mi) {
                    if (col >= 1024) {
                        const int rowb = bm + wr * 128 + mi * 16 + rq;
                        f16x4 q;
#pragma unroll
                        for (int r = 0; r < 4; ++r) q[r] = (f16)(acc[mi][nj][r] + bv_);
                        f16* Cp = (f16*)C2 + (size_t)(rowb >> 11) * 2048 * 1024 +
                                  (size_t)(col - 1024) * 2048;
                        *(f16x4*)&Cp[rowb & 2047] = q;
                    } else {
#pragma unroll
                        for (int r = 0; r < 4; ++r) {
                            const int row = bm + wr * 128 + mi * 16 + rq + r;
                            ((f16*)C1)[(size_t)row * 1024 + col] =
                                (f16)(acc[mi][nj][r] + bv_);
                        }
                    }
                }
            }
        }
        return;
    }
#undef STG_A
#undef STG_B
#undef LDA_
#undef LDB_
#undef MM
#undef PTILE
#undef PTAIL
}

// ---------------------------------------------------------------------------
extern "C" void kernel_launch(void* const* d_in, const int* in_sizes, int n_in,
                              void* d_out, int out_size, void* d_ws, size_t ws_size,
                              hipStream_t stream)
{
    const float* x   = (const float*)d_in[0];
    const float* enc = (const float*)d_in[1];
    const float* Wq  = (const float*)d_in[2];
    const float* bq  = (const float*)d_in[3];
    const float* Wk  = (const float*)d_in[4];
    const float* bk  = (const float*)d_in[5];
    const float* Wv  = (const float*)d_in[6];
    const float* bv  = (const float*)d_in[7];

    const size_t TOK = (size_t)16 * 2048;            // 32768 rows
    f16* Qh = (f16*)d_ws;                            // 64 MiB
    f16* Kh = Qh + TOK * 1024;                       // 64 MiB
    f16* Vt = Kh + TOK * 1024;                       // 64 MiB (V^T [16][1024][2048])
    f16* Wt = Vt + TOK * 1024;                       // 6 MiB ([Wq;Wk;Wv] f16, K-major)
    f16* S  = Wt + (size_t)3 * 1024 * 1024;          // 128 MiB (exp scores)
    f16* Xh = S;                                     // x in f16 (dead after proj)
    f16* Eh = S + TOK * 1024;                        // enc in f16 (dead after proj)
    float* Ppart = (float*)Wt;                       // 1 MiB (Wt dead after proj)

    // 1) fused prep: x->f16, enc->f16, weights->Wt
    prep_all<<<35840, 256, 0, stream>>>(x, enc, Wq, Wk, Wv, Xh, Eh, Wt);

    // 2) fused Q|K|V projections (one dispatch, 1536 blocks)
    gemm8<1024, 4><<<1536, 512, 0, stream>>>(
        Xh, Eh, Wt, bq, bk, bv, 0.03125f, Qh, Kh, Vt, nullptr,
        0, 0, 0, 1024, 128, 0);

    // 3) S = exp(Q K^T) + per-row partial sums
    gemm8<1024, 2><<<1024, 512, 0, stream>>>(
        Qh, nullptr, Kh, nullptr, nullptr, nullptr, 1.0f, S, nullptr, nullptr,
        Ppart,
        (size_t)2048 * 1024, (size_t)2048 * 1024, (size_t)2048 * 2048, 2048, 8, 8);

    // 4) H = (exp S) V * rowinv -> fp32 out (rowinv inlined from Ppart)
    gemm8<2048, 5><<<512, 512, 0, stream>>>(
        S, nullptr, Vt, nullptr, nullptr, nullptr, 1.0f, d_out, nullptr, nullptr,
        Ppart,
        (size_t)2048 * 2048, (size_t)1024 * 2048, (size_t)2048 * 1024, 1024, 8, 4);
}

// Round 20
// 624.326 us; speedup vs baseline: 6.2523x; 6.2523x over previous
//
#include <hip/hip_runtime.h>

typedef _Float16 f16;
typedef __attribute__((ext_vector_type(4))) _Float16 f16x4;
typedef __attribute__((ext_vector_type(8))) _Float16 f16x8;
typedef __attribute__((ext_vector_type(4))) float f32x4;

#define MFMA16(a, b, c) __builtin_amdgcn_mfma_f32_16x16x32_f16(a, b, c, 0, 0, 0)

__device__ __forceinline__ void gll16(const void* g, void* l) {
    __builtin_amdgcn_global_load_lds(
        (const __attribute__((address_space(1))) unsigned int*)g,
        (__attribute__((address_space(3))) unsigned int*)l, 16, 0, 0);
}

#define BAR() __builtin_amdgcn_s_barrier()
// RAW gate for global_load_lds -> ds_read; "memory" clobber only, no
// sched_barrier: compiler stays free to schedule fine-grained lgkmcnt.
#define VMC(n)  asm volatile("s_waitcnt vmcnt(" #n ")" ::: "memory")

// ---------------------------------------------------------------------------
// prep_all: fused {x->f16, enc->f16, W->Wt f16 transposed} in one dispatch.
// ---------------------------------------------------------------------------
__global__ __launch_bounds__(256) void prep_all(
    const float* __restrict__ x, const float* __restrict__ enc,
    const float* __restrict__ Wq, const float* __restrict__ Wk,
    const float* __restrict__ Wv,
    f16* __restrict__ Xh, f16* __restrict__ Eh, f16* __restrict__ Wt)
{
    const int bid = blockIdx.x;
    if (bid < 32768) {
        const float* in = (bid < 16384) ? x : enc;
        f16* out = (bid < 16384) ? Xh : Eh;
        const int b = bid & 16383;
        const size_t i = ((size_t)b * 256 + threadIdx.x) * 8;
        float4 a = *(const float4*)(in + i);
        float4 c = *(const float4*)(in + i + 4);
        f16x8 o;
        o[0] = (f16)a.x; o[1] = (f16)a.y; o[2] = (f16)a.z; o[3] = (f16)a.w;
        o[4] = (f16)c.x; o[5] = (f16)c.y; o[6] = (f16)c.z; o[7] = (f16)c.w;
        *(f16x8*)(out + i) = o;
        return;
    }
    __shared__ float tile[32][33];
    const int id2 = bid - 32768;
    const int w = id2 >> 10;
    const int r = id2 & 1023;
    const int n0 = (r & 31) * 32, k0 = (r >> 5) * 32;
    const float* W = w == 0 ? Wq : (w == 1 ? Wk : Wv);
    f16* dst = Wt + (size_t)w * 1024 * 1024;
    const int tx = threadIdx.x & 31, ty = threadIdx.x >> 5;
#pragma unroll
    for (int i = 0; i < 4; i++)
        tile[ty + i * 8][tx] = W[(size_t)(k0 + ty + i * 8) * 1024 + n0 + tx];
    __syncthreads();
#pragma unroll
    for (int i = 0; i < 4; i++)
        dst[(size_t)(n0 + ty + i * 8) * 1024 + k0 + tx] = (f16)tile[tx][ty + i * 8];
}

// ---------------------------------------------------------------------------
// 256x256 GEMM, 2-phase/tile schedule (4 barriers/tile, 32-MFMA clusters),
// compiler-scheduled waits (no setprio, no manual lgkmcnt — r14/r15 wins).
// BK=64 (128B rows) is load-bearing: 128B stage requests + L2-friendly
// working set + 8-slot conflict-free swizzle (r19's BK=32 broke all three).
// Gate derivation (FIFO, steady state entering phase A: outstanding=[A1(t)]):
//  phase A: reads A0,B0,B1(t); stage A0B0B1(t+1) (6 glls) -> VMC(6) retires A1(t).
//  phase B: reads A1(t); stage A1(t+1) (2) -> VMC(2) retires A0B0B1(t+1).
// Prologue VMC(2) establishes invariant; tail drains VMC(0).
// EPI: 2 = exp -> f16 S + per-row partial sums -> aux (QK^T)
//      4 = fused Q|K|V projections (blocks [0,512): Q; [512,1536): K|V)
//      5 = PV with inline row-sum inverse from aux
// ---------------------------------------------------------------------------
template <int KD, int EPI>
__global__ __launch_bounds__(512, 2) void gemm8(
    const f16* __restrict__ Ab, const f16* __restrict__ Ab2,
    const f16* __restrict__ Bb,
    const float* __restrict__ b0, const float* __restrict__ b1,
    const float* __restrict__ b2, float scale,
    void* __restrict__ C0, void* __restrict__ C1, void* __restrict__ C2,
    float* __restrict__ aux,
    size_t strA, size_t strB, size_t strC, int ldc, int nbx, int nby)
{
    __shared__ f16 shA[2 * 256 * 64];   // buffer d at d*16384 elems (d*32768 B)
    __shared__ f16 shB[2 * 256 * 64];

    int id = blockIdx.x;
    {
        const int chunk = (int)gridDim.x >> 3;
        id = (id & 7) * chunk + (id >> 3);
    }
    int bx, by, z;
    bool isQ = false;
    if constexpr (EPI == 4) {
        z = 0;
        isQ = (id < 512);
        if (isQ) { by = id & 3; bx = id >> 2; }
        else     { const int id2 = id - 512; by = id2 & 7; bx = id2 >> 3; }
    } else {
        by = id % nby;
        const int r2 = id / nby;
        bx = r2 % nbx;
        z  = r2 / nbx;
    }
    const int bm = bx * 256, bn = by * 256;

    const f16* A;
    const f16* B;
    if constexpr (EPI == 4) {
        A = isQ ? Ab : Ab2;
        B = Bb + (isQ ? (size_t)0 : (size_t)1024 * 1024);
    } else {
        A = Ab + (size_t)z * strA;
        B = Bb + (size_t)z * strB;
    }

    const int t = threadIdx.x, lane = t & 63, wid = t >> 6;
    const int wr = wid >> 2, wc = wid & 3;
    const int fr = lane & 15, kb = (lane >> 4) * 16;
    const int sw = (fr & 7) << 4;

    const int lsr = lane >> 3;
    const int lsc = ((lane & 7) * 16) ^ (lsr << 4);
    const int a_  = wid * 8;
    const int bq_ = (wid >> 2) * 64 + (wid & 3) * 8;
    const f16* aT0 = A + (size_t)(bm + lsr) * KD + (lsc >> 1) + (size_t)a_ * KD;
    const f16* bT0 = B + (size_t)(bn + lsr) * KD + (lsc >> 1) + (size_t)bq_ * KD;

    const char* Ab_ = (const char*)shA;
    const char* Bb_ = (const char*)shB;
    const int aoffk0 = (wr * 128 + fr) * 128 + (kb ^ sw);
    const int aoffk1 = (wr * 128 + fr) * 128 + ((64 | kb) ^ sw);
    const int boffk0 = (wc * 64 + fr) * 128 + (kb ^ sw);
    const int boffk1 = (wc * 64 + fr) * 128 + ((64 | kb) ^ sw);

#define STG_A0(d, kt) do {                                                    \
        const f16* As_ = aT0 + (size_t)(kt) * 64;                             \
        gll16(As_,                      shA + (d) * 16384 + (a_)*64);         \
        gll16(As_ + (size_t)128 * KD,   shA + (d) * 16384 + (128 + a_)*64); } while (0)
#define STG_A1(d, kt) do {                                                    \
        const f16* As_ = aT0 + (size_t)(kt) * 64;                             \
        gll16(As_ + (size_t)64 * KD,    shA + (d) * 16384 + (64 + a_)*64);    \
        gll16(As_ + (size_t)192 * KD,   shA + (d) * 16384 + (192 + a_)*64); } while (0)
#define STG_B0(d, kt) do {                                                    \
        const f16* Bs_ = bT0 + (size_t)(kt) * 64;                             \
        gll16(Bs_,                      shB + (d) * 16384 + (bq_)*64);        \
        gll16(Bs_ + (size_t)128 * KD,   shB + (d) * 16384 + (128 + bq_)*64); } while (0)
#define STG_B1(d, kt) do {                                                    \
        const f16* Bs_ = bT0 + (size_t)(kt) * 64;                             \
        gll16(Bs_ + (size_t)32 * KD,    shB + (d) * 16384 + (32 + bq_)*64);   \
        gll16(Bs_ + (size_t)160 * KD,   shB + (d) * 16384 + (160 + bq_)*64); } while (0)

    f16x8 af[2][2][4];     // [mh][kk][i]
    f16x8 bf[2][2][2];     // [nh][kk][j]
    f32x4 acc[8][4] = {};

#define LDA_(d, mh)                                                           \
    _Pragma("unroll") for (int i_ = 0; i_ < 4; ++i_) {                        \
        af[mh][0][i_] = *(const f16x8*)(Ab_ + (d) * 32768 + aoffk0 +          \
                                        ((mh) * 64 + i_ * 16) * 128);         \
        af[mh][1][i_] = *(const f16x8*)(Ab_ + (d) * 32768 + aoffk1 +          \
                                        ((mh) * 64 + i_ * 16) * 128);         \
    }
#define LDB_(d, nh)                                                           \
    _Pragma("unroll") for (int j_ = 0; j_ < 2; ++j_) {                        \
        bf[nh][0][j_] = *(const f16x8*)(Bb_ + (d) * 32768 + boffk0 +          \
                                        ((nh) * 32 + j_ * 16) * 128);         \
        bf[nh][1][j_] = *(const f16x8*)(Bb_ + (d) * 32768 + boffk1 +          \
                                        ((nh) * 32 + j_ * 16) * 128);         \
    }

#define MM(mh, nh)                                                            \
    _Pragma("unroll") for (int kk_ = 0; kk_ < 2; ++kk_)                       \
    _Pragma("unroll") for (int i_ = 0; i_ < 4; ++i_)                          \
    _Pragma("unroll") for (int j_ = 0; j_ < 2; ++j_)                          \
        acc[(mh) * 4 + i_][(nh) * 2 + j_] =                                   \
            MFMA16(af[mh][kk_][i_], bf[nh][kk_][j_],                          \
                   acc[(mh) * 4 + i_][(nh) * 2 + j_]);

// 2-phase tile: 4 barriers, 32-MFMA clusters, counted gates per derivation
#define TILE_FULL(d, kt)                                                      \
    do {                                                                      \
        LDA_(d, 0); LDB_(d, 0); LDB_(d, 1);                                   \
        STG_A0((d) ^ 1, (kt) + 1); STG_B0((d) ^ 1, (kt) + 1);                 \
        STG_B1((d) ^ 1, (kt) + 1);                                            \
        VMC(6);                                                               \
        BAR(); MM(0, 0); MM(0, 1); BAR();                                     \
        LDA_(d, 1);                                                           \
        STG_A1((d) ^ 1, (kt) + 1);                                            \
        VMC(2);                                                               \
        BAR(); MM(1, 1); MM(1, 0); BAR();                                     \
    } while (0)

#define TILE_TAIL(d)                                                          \
    do {                                                                      \
        LDA_(d, 0); LDB_(d, 0); LDB_(d, 1);                                   \
        VMC(0);                                                               \
        BAR(); MM(0, 0); MM(0, 1); BAR();                                     \
        LDA_(d, 1);                                                           \
        BAR(); MM(1, 1); MM(1, 0); BAR();                                     \
    } while (0)

    constexpr int NT = KD / 64;   // 16 or 32, always even

    // prologue: stage tile 0; retire A0B0B1(0), leave A1(0) in flight.
    STG_A0(0, 0); STG_B0(0, 0); STG_B1(0, 0); STG_A1(0, 0);
    VMC(2);
    BAR();

    for (int ti = 0; ti < NT - 2; ti += 2) {
        TILE_FULL(0, ti);
        TILE_FULL(1, ti + 1);
    }
    TILE_FULL(0, NT - 2);
    TILE_TAIL(1);

    const int fc = lane & 15, rq = (lane >> 4) * 4;

    if constexpr (EPI == 2) {
        BAR();   // reuse shA as part[256][4]
        float* part = (float*)shA;
        f16* Sp = (f16*)C0 + (size_t)z * strC;
#pragma unroll
        for (int mi = 0; mi < 8; ++mi)
#pragma unroll
            for (int r = 0; r < 4; ++r) {
                const int rl = wr * 128 + mi * 16 + rq + r;
                float ps = 0.f;
#pragma unroll
                for (int nj = 0; nj < 4; ++nj) {
                    const int col = bn + wc * 64 + nj * 16 + fc;
                    f16 eh = (f16)__expf(acc[mi][nj][r]);
                    ps += (float)eh;
                    Sp[(size_t)(bm + rl) * ldc + col] = eh;
                }
#pragma unroll
                for (int o = 1; o < 16; o <<= 1) ps += __shfl_xor(ps, o);
                if (fc == 0) part[rl * 4 + wc] = ps;
            }
        BAR();
        if (t < 256) {
            const float4 p4 = *(const float4*)(part + t * 4);
            aux[((size_t)z * 2048 + bm + t) * 8 + by] = p4.x + p4.y + p4.z + p4.w;
        }
        return;
    }

    if constexpr (EPI == 5) {
        float invr[8][4];
#pragma unroll
        for (int mi = 0; mi < 8; ++mi)
#pragma unroll
            for (int r = 0; r < 4; ++r) {
                const int row = bm + wr * 128 + mi * 16 + rq + r;
                const float4* p = (const float4*)(aux + ((size_t)z * 2048 + row) * 8);
                const float4 a = p[0], b = p[1];
                invr[mi][r] = 1.0f / (a.x + a.y + a.z + a.w + b.x + b.y + b.z + b.w);
            }
#pragma unroll
        for (int nj = 0; nj < 4; ++nj) {
            const int col = bn + wc * 64 + nj * 16 + fc;
#pragma unroll
            for (int mi = 0; mi < 8; ++mi)
#pragma unroll
                for (int r = 0; r < 4; ++r) {
                    const int row = bm + wr * 128 + mi * 16 + rq + r;
                    ((float*)C0 + (size_t)z * strC)[(size_t)row * ldc + col] =
                        acc[mi][nj][r] * invr[mi][r];
                }
        }
        return;
    }

    if constexpr (EPI == 4) {
#pragma unroll
        for (int nj = 0; nj < 4; ++nj) {
            const int col = bn + wc * 64 + nj * 16 + fc;
            if (isQ) {
                const float bv_ = b0[col];
#pragma unroll
                for (int mi = 0; mi < 8; ++mi)
#pragma unroll
                    for (int r = 0; r < 4; ++r) {
                        const int row = bm + wr * 128 + mi * 16 + rq + r;
                        ((f16*)C0)[(size_t)row * 1024 + col] =
                            (f16)((acc[mi][nj][r] + bv_) * scale);
                    }
            } else {
                const float bv_ = (col < 1024) ? b1[col] : b2[col - 1024];
#pragma unroll
                for (int mi = 0; mi < 8; ++mi) {
                    if (col >= 1024) {
                        const int rowb = bm + wr * 128 + mi * 16 + rq;
                        f16x4 q;
#pragma unroll
                        for (int r = 0; r < 4; ++r) q[r] = (f16)(acc[mi][nj][r] + bv_);
                        f16* Cp = (f16*)C2 + (size_t)(rowb >> 11) * 2048 * 1024 +
                                  (size_t)(col - 1024) * 2048;
                        *(f16x4*)&Cp[rowb & 2047] = q;
                    } else {
#pragma unroll
                        for (int r = 0; r < 4; ++r) {
                            const int row = bm + wr * 128 + mi * 16 + rq + r;
                            ((f16*)C1)[(size_t)row * 1024 + col] =
                                (f16)(acc[mi][nj][r] + bv_);
                        }
                    }
                }
            }
        }
        return;
    }
#undef STG_A0
#undef STG_A1
#undef STG_B0
#undef STG_B1
#undef LDA_
#undef LDB_
#undef MM
#undef TILE_FULL
#undef TILE_TAIL
}

// ---------------------------------------------------------------------------
extern "C" void kernel_launch(void* const* d_in, const int* in_sizes, int n_in,
                              void* d_out, int out_size, void* d_ws, size_t ws_size,
                              hipStream_t stream)
{
    const float* x   = (const float*)d_in[0];
    const float* enc = (const float*)d_in[1];
    const float* Wq  = (const float*)d_in[2];
    const float* bq  = (const float*)d_in[3];
    const float* Wk  = (const float*)d_in[4];
    const float* bk  = (const float*)d_in[5];
    const float* Wv  = (const float*)d_in[6];
    const float* bv  = (const float*)d_in[7];

    const size_t TOK = (size_t)16 * 2048;            // 32768 rows
    f16* Qh = (f16*)d_ws;                            // 64 MiB
    f16* Kh = Qh + TOK * 1024;                       // 64 MiB
    f16* Vt = Kh + TOK * 1024;                       // 64 MiB (V^T [16][1024][2048])
    f16* Wt = Vt + TOK * 1024;                       // 6 MiB ([Wq;Wk;Wv] f16, K-major)
    f16* S  = Wt + (size_t)3 * 1024 * 1024;          // 128 MiB (exp scores)
    f16* Xh = S;                                     // x in f16 (dead after proj)
    f16* Eh = S + TOK * 1024;                        // enc in f16 (dead after proj)
    float* Ppart = (float*)Wt;                       // 1 MiB (Wt dead after proj)

    // 1) fused prep: x->f16, enc->f16, weights->Wt
    prep_all<<<35840, 256, 0, stream>>>(x, enc, Wq, Wk, Wv, Xh, Eh, Wt);

    // 2) fused Q|K|V projections (one dispatch, 1536 blocks)
    gemm8<1024, 4><<<1536, 512, 0, stream>>>(
        Xh, Eh, Wt, bq, bk, bv, 0.03125f, Qh, Kh, Vt, nullptr,
        0, 0, 0, 1024, 128, 0);

    // 3) S = exp(Q K^T) + per-row partial sums
    gemm8<1024, 2><<<1024, 512, 0, stream>>>(
        Qh, nullptr, Kh, nullptr, nullptr, nullptr, 1.0f, S, nullptr, nullptr,
        Ppart,
        (size_t)2048 * 1024, (size_t)2048 * 1024, (size_t)2048 * 2048, 2048, 8, 8);

    // 4) H = (exp S) V * rowinv -> fp32 out (rowinv inlined from Ppart)
    gemm8<2048, 5><<<512, 512, 0, stream>>>(
        S, nullptr, Vt, nullptr, nullptr, nullptr, 1.0f, d_out, nullptr, nullptr,
        Ppart,
        (size_t)2048 * 2048, (size_t)1024 * 2048, (size_t)2048 * 1024, 1024, 8, 4);
}